// Round 10
// baseline (274.917 us; speedup 1.0000x reference)
//
#include <hip/hip_runtime.h>

#define NTOK 49
#define CC   128
#define NHEADS 4
#define HWW  56
#define HW2  3136
#define SCALE_F 0.17677669529663687f

typedef __attribute__((ext_vector_type(8))) short s16x8;
typedef __attribute__((ext_vector_type(4))) float f32x4;
typedef __attribute__((ext_vector_type(16))) float f32x16;
typedef __attribute__((ext_vector_type(2))) unsigned int u32x2;

static __device__ __forceinline__ unsigned short f2bf(float f) {
  unsigned int u = __float_as_uint(f);
  u += 0x7fffu + ((u >> 16) & 1u);
  return (unsigned short)(u >> 16);
}
static __device__ __forceinline__ float bf2f(unsigned short h) {
  return __uint_as_float(((unsigned int)h) << 16);
}
// HW packed f32->bf16 (RNE), 1 VALU op for 2 values
static __device__ __forceinline__ unsigned int cvtpk(float lo, float hi) {
  unsigned int r;
  asm("v_cvt_pk_bf16_f32 %0, %1, %2" : "=v"(r) : "v"(lo), "v"(hi));
  return r;
}
// row-keyed bijective swizzle: flips col bits 3-5 by row&7 and bit 6 by row bit 3
// -> 16 bank-slot spread (was 8). Keeps 8-elem (16B) groups contiguous.
// Used by ALL writers/readers of Buf0/1/2.
static __device__ __forceinline__ int swz8(int row, int col) {
  return col ^ ((row & 7) << 3) ^ ((row & 8) << 3);
}

union FragU { s16x8 v; unsigned int u[4]; };

// prep: weights -> bf16 (scale folded into Wq) + bias table Biasg[h][k][q]
__global__ void prep_kernel(const float* __restrict__ Wq, const float* __restrict__ Wk,
                            const float* __restrict__ Wv, const float* __restrict__ Wo,
                            const float* __restrict__ rpb,
                            unsigned short* __restrict__ dstW, float* __restrict__ dstB) {
  int i = blockIdx.x * 256 + threadIdx.x;
  if (i < 65536) {
    const float* src = (i < 16384) ? Wq : (i < 32768) ? Wk : (i < 49152) ? Wv : Wo;
    float v = src[i & 16383];
    if (i < 16384) v *= SCALE_F;
    dstW[i] = f2bf(v);
  } else {
    int j = i - 65536;
    if (j < NHEADS*NTOK*NTOK) {
      int h = j / (NTOK*NTOK), rem = j - h*(NTOK*NTOK);
      int k = rem / NTOK, q = rem - k*NTOK;
      int qi = q/7, qj = q - qi*7, ki = k/7, kj = k - ki*7;
      dstB[j] = rpb[((qi-ki+6)*13 + (qj-kj+6))*NHEADS + h];
    }
  }
}

__global__ __launch_bounds__(256, 3)
void winattn_kernel(const float* __restrict__ Xq, const float* __restrict__ Xk,
                    const float* __restrict__ Xv,
                    const unsigned short* __restrict__ Wbf,
                    const float* __restrict__ Biasg,
                    const float* __restrict__ bq, const float* __restrict__ bk,
                    const float* __restrict__ bv, const float* __restrict__ bo,
                    float* __restrict__ out_x,
                    float* __restrict__ out_ctx)
{
  // 52736 B total -> 3 blocks/CU (158208 <= 163840)
  __shared__ alignas(16) unsigned short smem[26368];
  unsigned short* Buf0 = smem;            // [49][128] raw q -> Q -> attn-out (swz8)
  unsigned short* Buf1 = smem + 6272;     // [49][128] raw k -> K (swz8)
  unsigned short* VT   = smem + 12544;    // [128][56]: (h*32+d) x token, V^T
  unsigned short* Buf2 = smem + 19712;    // [49][128] raw v (swz8) -> P bounce [4][32*52]
  float* Obnc = (float*)(smem + 12544);   // epilogue bounce [4 waves][32ch][49tok] stride 50

  const int tid = threadIdx.x;
  const int wv  = tid >> 6;
  const int l   = tid & 63;
  const int lr  = l & 15;   // 16x16 MFMA lane row/col
  const int lg  = l >> 4;   // 16x16 MFMA k-group
  const int c31 = l & 31;   // 32x32 MFMA lane col
  const int hi  = l >> 5;   // 32x32 MFMA half

  // XCD-bijective swizzle (4096 % 8 == 0): same-band windows share an XCD L2
  const int win  = (blockIdx.x & 7) * 512 + (blockIdx.x >> 3);
  const int bimg = win >> 6;
  const int r0   = ((win >> 3) & 7) * 7;
  const int c0   = (win & 7) * 7;

  // ---- Phase 0: zero VT + stage q,k,v (lane=token; b64 LDS stores, cvt_pk packing)
  {
    unsigned int* vz = (unsigned int*)VT;
    #pragma unroll
    for (int i = 0; i < 14; ++i) vz[tid + i*256] = 0u;   // 14336 B
    int s = tid & 63, g = tid >> 6;
    if (s < NTOK) {
      int si = s / 7, sj = s - si*7;
      size_t base = (size_t)bimg*CC*HW2 + (size_t)(r0+si)*HWW + (c0+sj);
      #pragma unroll 4
      for (int cp = 0; cp < 8; ++cp) {
        int ci = g*32 + cp*4;
        size_t off = base + (size_t)ci * HW2;
        float q0 = Xq[off], q1 = Xq[off+HW2], q2 = Xq[off+2*HW2], q3 = Xq[off+3*HW2];
        float k0 = Xk[off], k1 = Xk[off+HW2], k2 = Xk[off+2*HW2], k3 = Xk[off+3*HW2];
        float v0 = Xv[off], v1 = Xv[off+HW2], v2 = Xv[off+2*HW2], v3 = Xv[off+3*HW2];
        int di = s*CC + swz8(s, ci);                  // 8B-aligned (swz8 keeps bits 0-2)
        u32x2 pq = {cvtpk(q0,q1), cvtpk(q2,q3)};
        u32x2 pk = {cvtpk(k0,k1), cvtpk(k2,k3)};
        u32x2 pv = {cvtpk(v0,v1), cvtpk(v2,v3)};
        *(u32x2*)(Buf0 + di) = pq;
        *(u32x2*)(Buf1 + di) = pk;
        *(u32x2*)(Buf2 + di) = pv;
      }
    }
  }
  __syncthreads();

  // proj read-half: acc[mt][ntl] = src * W^T (bias folded at write)
  auto projR = [&](const unsigned short* __restrict__ src, const unsigned short* __restrict__ Wg,
                   const float* __restrict__ bias, float bscale,
                   f32x4 (&acc)[4][2], float (&bb)[2]) {
    s16x8 bfr[2][4];
    #pragma unroll
    for (int ntl = 0; ntl < 2; ++ntl) {
      int col = wv*32 + ntl*16 + lr;
      bb[ntl] = bias[col] * bscale;
      #pragma unroll
      for (int ks = 0; ks < 4; ++ks)
        bfr[ntl][ks] = *(const s16x8*)(Wg + col*CC + ks*32 + lg*8);
    }
    #pragma unroll
    for (int mt = 0; mt < 4; ++mt) {
      int ar = mt*16 + lr;
      s16x8 af[4];
      #pragma unroll
      for (int ks = 0; ks < 4; ++ks)
        af[ks] = *(const s16x8*)(src + ar*CC + swz8(ar, ks*32 + lg*8));
      #pragma unroll
      for (int ntl = 0; ntl < 2; ++ntl) {
        f32x4 a = {0.f,0.f,0.f,0.f};
        #pragma unroll
        for (int ks = 0; ks < 4; ++ks)
          a = __builtin_amdgcn_mfma_f32_16x16x32_bf16(af[ks], bfr[ntl][ks], a, 0,0,0);
        acc[mt][ntl] = a;
      }
    }
  };
  auto projW = [&](unsigned short* __restrict__ dst, f32x4 (&acc)[4][2], float (&bb)[2]) {
    #pragma unroll
    for (int mt = 0; mt < 4; ++mt) {
      #pragma unroll
      for (int ntl = 0; ntl < 2; ++ntl) {
        int col = wv*32 + ntl*16 + lr;
        int row0 = mt*16 + lg*4;          // C/D: row=(l>>4)*4+r, col=l&15
        unsigned int p01 = cvtpk(acc[mt][ntl][0]+bb[ntl], acc[mt][ntl][1]+bb[ntl]);
        unsigned int p23 = cvtpk(acc[mt][ntl][2]+bb[ntl], acc[mt][ntl][3]+bb[ntl]);
        if (row0   < NTOK) dst[ row0   *CC + swz8(row0,  col)] = (unsigned short)p01;
        if (row0+1 < NTOK) dst[(row0+1)*CC + swz8(row0+1,col)] = (unsigned short)(p01>>16);
        if (row0+2 < NTOK) dst[(row0+2)*CC + swz8(row0+2,col)] = (unsigned short)p23;
        if (row0+3 < NTOK) dst[(row0+3)*CC + swz8(row0+3,col)] = (unsigned short)(p23>>16);
      }
    }
  };

  // ---- Merged projection phase: all reads before ONE barrier, writes after.
  // V first (its LDS write targets VT, a distinct region -> safe pre-barrier,
  // and accV dies early, bounding register pressure).
  {
    f32x4 accV[4][2]; float bbV[2];
    projR(Buf2, Wbf + 32768, bv, 1.f, accV, bbV);
    #pragma unroll
    for (int mt = 0; mt < 4; ++mt) {
      #pragma unroll
      for (int ntl = 0; ntl < 2; ++ntl) {
        int col = wv*32 + ntl*16 + lr;
        int row0 = mt*16 + lg*4;          // token, even -> u32 aligned
        unsigned int p01 = cvtpk(accV[mt][ntl][0]+bbV[ntl], accV[mt][ntl][1]+bbV[ntl]);
        unsigned int p23 = cvtpk(accV[mt][ntl][2]+bbV[ntl], accV[mt][ntl][3]+bbV[ntl]);
        int vbse = col*56 + row0;
        if (row0+1 < NTOK) *(unsigned int*)(VT + vbse) = p01;
        else if (row0 < NTOK) VT[vbse] = (unsigned short)p01;
        if (row0+3 < NTOK) *(unsigned int*)(VT + vbse + 2) = p23;
        else if (row0+2 < NTOK) VT[vbse+2] = (unsigned short)p23;
      }
    }
  }
  f32x4 accQ[4][2], accK[4][2]; float bbQ[2], bbK[2];
  projR(Buf0, Wbf,         bq, SCALE_F, accQ, bbQ);    // Q (scaled)
  projR(Buf1, Wbf + 16384, bk, 1.f,     accK, bbK);    // K
  __syncthreads();
  projW(Buf0, accQ, bbQ);                              // Buf0 = Q
  projW(Buf1, accK, bbK);                              // Buf1 = K
  __syncthreads();

  // ---- Head section: wave wv owns head h=wv. S^T = K·Q^T via 32x32x16 MFMA.
  {
    const int h = wv;
    const float* Bh = Biasg + h*(NTOK*NTOK);   // [k][q], lane-consecutive in q
    s16x8 ak[2][2], av[4];
    #pragma unroll
    for (int kt = 0; kt < 2; ++kt) {
      int krow = kt*32 + c31; if (krow > 48) krow = 48;   // clamped rows masked later
      #pragma unroll
      for (int ks = 0; ks < 2; ++ks)
        ak[kt][ks] = *(const s16x8*)(Buf1 + krow*CC + swz8(krow, h*32 + ks*16 + hi*8));
    }
    #pragma unroll
    for (int kk = 0; kk < 4; ++kk)
      av[kk] = *(const s16x8*)(VT + (h*32 + c31)*56 + kk*16 + hi*8);
    size_t cbase = ((size_t)win*NHEADS + h)*(NTOK*NTOK);
    unsigned short* PL = Buf2 + h*1664;    // wave-local bounce [32][52] bf16 (8B rows)

    #pragma unroll
    for (int qh = 0; qh < 2; ++qh) {
      int q = qh*32 + c31;
      int qrow = q > 48 ? 48 : q;
      s16x8 bqf[2];
      #pragma unroll
      for (int ks = 0; ks < 2; ++ks)
        bqf[ks] = *(const s16x8*)(Buf0 + qrow*CC + swz8(qrow, h*32 + ks*16 + hi*8));
      f32x16 s0 = {0,0,0,0,0,0,0,0,0,0,0,0,0,0,0,0};
      f32x16 s1 = {0,0,0,0,0,0,0,0,0,0,0,0,0,0,0,0};
      __builtin_amdgcn_s_setprio(1);
      s0 = __builtin_amdgcn_mfma_f32_32x32x16_bf16(ak[0][0], bqf[0], s0, 0,0,0);
      s0 = __builtin_amdgcn_mfma_f32_32x32x16_bf16(ak[0][1], bqf[1], s0, 0,0,0);
      s1 = __builtin_amdgcn_mfma_f32_32x32x16_bf16(ak[1][0], bqf[0], s1, 0,0,0);
      s1 = __builtin_amdgcn_mfma_f32_32x32x16_bf16(ak[1][1], bqf[1], s1, 0,0,0);
      __builtin_amdgcn_s_setprio(0);
      // bias (precomputed table) + mask; D row=(r&3)+8*(r>>2)+4*hi, col=q
      float mx = -1e30f;
      #pragma unroll
      for (int r = 0; r < 16; ++r) {
        int kb = (r&3) + 8*(r>>2) + 4*hi;
        float v0 = -1e30f, v1 = -1e30f;
        if (q < NTOK) {
          v0 = s0[r] + Bh[kb*NTOK + q];
          if (kb + 32 < NTOK) v1 = s1[r] + Bh[(kb+32)*NTOK + q];
        }
        s0[r] = v0; mx = fmaxf(mx, v0);
        s1[r] = v1; mx = fmaxf(mx, v1);
      }
      mx = fmaxf(mx, __shfl_xor(mx, 32));
      float sum = 0.f;
      #pragma unroll
      for (int r = 0; r < 16; ++r) { s0[r] = __expf(s0[r]-mx); sum += s0[r]; }
      #pragma unroll
      for (int r = 0; r < 16; ++r) { s1[r] = __expf(s1[r]-mx); sum += s1[r]; }
      sum += __shfl_xor(sum, 32);
      float rinv = 1.f / sum;
      #pragma unroll
      for (int r = 0; r < 16; ++r) { s0[r] *= rinv; s1[r] *= rinv; }   // normalize
      // stash normalized P^T half: b64 stores, 4 consecutive k per group
      if (q < NTOK) {
        #pragma unroll
        for (int g = 0; g < 4; ++g) {
          u32x2 w;
          w[0] = cvtpk(s0[4*g],   s0[4*g+1]);
          w[1] = cvtpk(s0[4*g+2], s0[4*g+3]);
          *(u32x2*)(PL + c31*52 + g*8 + 4*hi) = w;
          int k2 = g*8 + 4*hi + 32;
          if (k2 <= 48) {
            u32x2 w2;
            w2[0] = cvtpk(s1[4*g],   s1[4*g+1]);
            w2[1] = cvtpk(s1[4*g+2], s1[4*g+3]);
            *(u32x2*)(PL + c31*52 + k2) = w2;
          }
        }
      }
      // PV: pack P^T bf16, exchange halves, out^T = V^T · P^T
      f32x16 pacc = {0,0,0,0,0,0,0,0,0,0,0,0,0,0,0,0};
      auto pvstep = [&](f32x16& e, const s16x8& a0, const s16x8& a1) {
        unsigned int w0m0 = cvtpk(e[0],e[1]),   w0m1 = cvtpk(e[2],e[3]);
        unsigned int w1m0 = cvtpk(e[4],e[5]),   w1m1 = cvtpk(e[6],e[7]);
        unsigned int w2m0 = cvtpk(e[8],e[9]),   w2m1 = cvtpk(e[10],e[11]);
        unsigned int w3m0 = cvtpk(e[12],e[13]), w3m1 = cvtpk(e[14],e[15]);
        unsigned int p0m0 = __shfl_xor((int)w0m0,32), p0m1 = __shfl_xor((int)w0m1,32);
        unsigned int p1m0 = __shfl_xor((int)w1m0,32), p1m1 = __shfl_xor((int)w1m1,32);
        unsigned int p2m0 = __shfl_xor((int)w2m0,32), p2m1 = __shfl_xor((int)w2m1,32);
        unsigned int p3m0 = __shfl_xor((int)w3m0,32), p3m1 = __shfl_xor((int)w3m1,32);
        FragU f;
        f.u[0] = hi ? p1m0 : w0m0;  f.u[1] = hi ? p1m1 : w0m1;
        f.u[2] = hi ? w1m0 : p0m0;  f.u[3] = hi ? w1m1 : p0m1;
        __builtin_amdgcn_s_setprio(1);
        pacc = __builtin_amdgcn_mfma_f32_32x32x16_bf16(a0, f.v, pacc, 0,0,0);
        f.u[0] = hi ? p3m0 : w2m0;  f.u[1] = hi ? p3m1 : w2m1;
        f.u[2] = hi ? w3m0 : p2m0;  f.u[3] = hi ? w3m1 : p2m1;
        pacc = __builtin_amdgcn_mfma_f32_32x32x16_bf16(a1, f.v, pacc, 0,0,0);
        __builtin_amdgcn_s_setprio(0);
      };
      pvstep(s0, av[0], av[1]);
      pvstep(s1, av[2], av[3]);
      { // coalesced ctx dump (wave-local; stride-52 rows)
        const int cnt = (qh == 0) ? 32*NTOK : 17*NTOK;
        size_t gb = cbase + (size_t)qh*32*NTOK;
        #pragma unroll
        for (int base = 0; base < 32*NTOK; base += 64) {
          int idx = base + l;
          if (idx < cnt) {
            int qq = idx / NTOK, kk2 = idx - qq*NTOK;
            out_ctx[gb + idx] = bf2f(PL[qq*52 + kk2]);
          }
        }
      }
      if (q < NTOK) { // attn-out into dead Q cols (bijective swz8 -> no collisions)
        #pragma unroll
        for (int r = 0; r < 16; ++r) {
          int d = (r&3) + 8*(r>>2) + 4*hi;
          Buf0[q*CC + swz8(q, h*32 + d)] = f2bf(pacc[r]);
        }
      }
    }
  }
  __syncthreads();

  { // output projection: x = attn_out @ Wo^T + bo, via LDS bounce (VT/Buf2 dead)
    const unsigned short* Wg = Wbf + 49152;
    float* Of = Obnc + wv*1600;     // [32ch][49tok] stride 50
    s16x8 bfr[2][4]; float ob[2];
    #pragma unroll
    for (int ntl = 0; ntl < 2; ++ntl) {
      int col = wv*32 + ntl*16 + lr;
      ob[ntl] = bo[col];
      #pragma unroll
      for (int ks = 0; ks < 4; ++ks)
        bfr[ntl][ks] = *(const s16x8*)(Wg + col*CC + ks*32 + lg*8);
    }
    #pragma unroll
    for (int mt = 0; mt < 4; ++mt) {
      int ar = mt*16 + lr;
      s16x8 af[4];
      #pragma unroll
      for (int ks = 0; ks < 4; ++ks)
        af[ks] = *(const s16x8*)(Buf0 + ar*CC + swz8(ar, ks*32 + lg*8));
      #pragma unroll
      for (int ntl = 0; ntl < 2; ++ntl) {
        f32x4 a = {0.f,0.f,0.f,0.f};
        #pragma unroll
        for (int ks = 0; ks < 4; ++ks)
          a = __builtin_amdgcn_mfma_f32_16x16x32_bf16(af[ks], bfr[ntl][ks], a, 0,0,0);
        #pragma unroll
        for (int r = 0; r < 4; ++r) {
          int row = mt*16 + lg*4 + r;
          if (row < NTOK)
            Of[(ntl*16 + lr)*50 + row] = a[r] + ob[ntl];
        }
      }
    }
    // wave-local dump: lane=linear element -> ~10 lines/inst instead of 64
    int chb = bimg*CC + wv*32;
    #pragma unroll
    for (int it = 0; it < 25; ++it) {
      int e = it*64 + l;
      if (e < 32*NTOK) {
        int ch = e / NTOK, tok = e - ch*NTOK;
        int si = tok / 7, sj = tok - si*7;
        out_x[(size_t)(chb + ch)*HW2 + (size_t)(r0+si)*HWW + (c0+sj)] = Of[ch*50 + tok];
      }
    }
  }
}

extern "C" void kernel_launch(void* const* d_in, const int* in_sizes, int n_in,
                              void* d_out, int out_size, void* d_ws, size_t ws_size,
                              hipStream_t stream) {
  (void)in_sizes; (void)n_in; (void)out_size; (void)ws_size;
  const float* query = (const float*)d_in[0];
  const float* key   = (const float*)d_in[1];
  const float* value = (const float*)d_in[2];
  const float* Wq = (const float*)d_in[3];
  const float* bq = (const float*)d_in[4];
  const float* Wk = (const float*)d_in[5];
  const float* bk = (const float*)d_in[6];
  const float* Wv = (const float*)d_in[7];
  const float* bv = (const float*)d_in[8];
  const float* Wo = (const float*)d_in[9];
  const float* bo = (const float*)d_in[10];
  const float* rpb = (const float*)d_in[11];

  unsigned short* Wbf = (unsigned short*)d_ws;                  // 128 KB bf16 weights
  float* Biasg = (float*)((char*)d_ws + 131072);                // 38.4 KB bias table
  float* out_x   = (float*)d_out;                               // [64][128][56][56] fp32
  float* out_ctx = out_x + (size_t)64*CC*HW2;                   // [4096][4][49][49] fp32

  prep_kernel<<<294, 256, 0, stream>>>(Wq, Wk, Wv, Wo, rpb, Wbf, Biasg);
  winattn_kernel<<<4096, 256, 0, stream>>>(query, key, value, Wbf, Biasg,
                                           bq, bk, bv, bo, out_x, out_ctx);
}

// Round 11
// 266.018 us; speedup vs baseline: 1.0335x; 1.0335x over previous
//
#include <hip/hip_runtime.h>

#define NTOK 49
#define CC   128
#define NHEADS 4
#define HWW  56
#define HW2  3136
#define SCALE_F 0.17677669529663687f

typedef __attribute__((ext_vector_type(8))) short s16x8;
typedef __attribute__((ext_vector_type(4))) float f32x4;
typedef __attribute__((ext_vector_type(16))) float f32x16;
typedef __attribute__((ext_vector_type(2))) unsigned int u32x2;

static __device__ __forceinline__ unsigned short f2bf(float f) {
  unsigned int u = __float_as_uint(f);
  u += 0x7fffu + ((u >> 16) & 1u);
  return (unsigned short)(u >> 16);
}
static __device__ __forceinline__ float bf2f(unsigned short h) {
  return __uint_as_float(((unsigned int)h) << 16);
}
// HW packed f32->bf16 (RNE), 1 VALU op for 2 values
static __device__ __forceinline__ unsigned int cvtpk(float lo, float hi) {
  unsigned int r;
  asm("v_cvt_pk_bf16_f32 %0, %1, %2" : "=v"(r) : "v"(lo), "v"(hi));
  return r;
}
// row-keyed bijective swizzle: flips col bits 3-5 by row&7, bit 6 by row bit 3
// -> 16 bank-slot spread; keeps 8-elem groups contiguous. ALL Buf0/1/2 access.
static __device__ __forceinline__ int swz8(int row, int col) {
  return col ^ ((row & 7) << 3) ^ ((row & 8) << 3);
}

union FragU { s16x8 v; unsigned int u[4]; };

// prep: weights -> bf16 (scale folded into Wq) + bias table Biasg[h][k][q]
__global__ void prep_kernel(const float* __restrict__ Wq, const float* __restrict__ Wk,
                            const float* __restrict__ Wv, const float* __restrict__ Wo,
                            const float* __restrict__ rpb,
                            unsigned short* __restrict__ dstW, float* __restrict__ dstB) {
  int i = blockIdx.x * 256 + threadIdx.x;
  if (i < 65536) {
    const float* src = (i < 16384) ? Wq : (i < 32768) ? Wk : (i < 49152) ? Wv : Wo;
    float v = src[i & 16383];
    if (i < 16384) v *= SCALE_F;
    dstW[i] = f2bf(v);
  } else {
    int j = i - 65536;
    if (j < NHEADS*NTOK*NTOK) {
      int h = j / (NTOK*NTOK), rem = j - h*(NTOK*NTOK);
      int k = rem / NTOK, q = rem - k*NTOK;
      int qi = q/7, qj = q - qi*7, ki = k/7, kj = k - ki*7;
      dstB[j] = rpb[((qi-ki+6)*13 + (qj-kj+6))*NHEADS + h];
    }
  }
}

__global__ __launch_bounds__(256, 3)
void winattn_kernel(const float* __restrict__ Xq, const float* __restrict__ Xk,
                    const float* __restrict__ Xv,
                    const unsigned short* __restrict__ Wbf,
                    const float* __restrict__ Biasg,
                    const float* __restrict__ bq, const float* __restrict__ bk,
                    const float* __restrict__ bv, const float* __restrict__ bo,
                    float* __restrict__ out_x,
                    float* __restrict__ out_ctx)
{
  // 52736 B total -> 3 blocks/CU
  __shared__ alignas(16) unsigned short smem[26368];
  unsigned short* Buf0 = smem;            // [49][128] raw q -> Q -> attn-out (swz8)
  unsigned short* Buf1 = smem + 6272;     // [49][128] raw k -> K (swz8)
  unsigned short* VT   = smem + 12544;    // [128][56]: (h*32+d) x token, V^T
  unsigned short* Buf2 = smem + 19712;    // [49][128] raw v (swz8) -> P bounce [4][32*52]
  float* Obnc = (float*)(smem + 12544);   // epilogue bounce [4 waves][32ch][49tok] stride 50

  const int tid = threadIdx.x;
  const int wv  = tid >> 6;
  const int l   = tid & 63;
  const int lr  = l & 15;   // 16x16 MFMA lane row/col
  const int lg  = l >> 4;   // 16x16 MFMA k-group
  const int c31 = l & 31;   // 32x32 MFMA lane col
  const int hi  = l >> 5;   // 32x32 MFMA half

  // XCD-bijective swizzle (4096 % 8 == 0): same-band windows share an XCD L2
  const int win  = (blockIdx.x & 7) * 512 + (blockIdx.x >> 3);
  const int bimg = win >> 6;
  const int r0   = ((win >> 3) & 7) * 7;
  const int c0   = (win & 7) * 7;

  // ---- Phase 0: zero VT + stage q,k,v (lane=token; b64 LDS stores, cvt_pk packing)
  {
    unsigned int* vz = (unsigned int*)VT;
    #pragma unroll
    for (int i = 0; i < 14; ++i) vz[tid + i*256] = 0u;   // 14336 B
    int s = tid & 63, g = tid >> 6;
    if (s < NTOK) {
      int si = s / 7, sj = s - si*7;
      size_t base = (size_t)bimg*CC*HW2 + (size_t)(r0+si)*HWW + (c0+sj);
      #pragma unroll 4
      for (int cp = 0; cp < 8; ++cp) {
        int ci = g*32 + cp*4;
        size_t off = base + (size_t)ci * HW2;
        float q0 = Xq[off], q1 = Xq[off+HW2], q2 = Xq[off+2*HW2], q3 = Xq[off+3*HW2];
        float k0 = Xk[off], k1 = Xk[off+HW2], k2 = Xk[off+2*HW2], k3 = Xk[off+3*HW2];
        float v0 = Xv[off], v1 = Xv[off+HW2], v2 = Xv[off+2*HW2], v3 = Xv[off+3*HW2];
        int di = s*CC + swz8(s, ci);                  // 8B-aligned (swz8 keeps bits 0-2)
        u32x2 pq = {cvtpk(q0,q1), cvtpk(q2,q3)};
        u32x2 pk = {cvtpk(k0,k1), cvtpk(k2,k3)};
        u32x2 pv = {cvtpk(v0,v1), cvtpk(v2,v3)};
        *(u32x2*)(Buf0 + di) = pq;
        *(u32x2*)(Buf1 + di) = pk;
        *(u32x2*)(Buf2 + di) = pv;
      }
    }
  }
  __syncthreads();

  // proj read-half: acc[mt][ntl] = src * W^T (bias folded at write)
  auto projR = [&](const unsigned short* __restrict__ src, const unsigned short* __restrict__ Wg,
                   const float* __restrict__ bias, float bscale,
                   f32x4 (&acc)[4][2], float (&bb)[2]) {
    s16x8 bfr[2][4];
    #pragma unroll
    for (int ntl = 0; ntl < 2; ++ntl) {
      int col = wv*32 + ntl*16 + lr;
      bb[ntl] = bias[col] * bscale;
      #pragma unroll
      for (int ks = 0; ks < 4; ++ks)
        bfr[ntl][ks] = *(const s16x8*)(Wg + col*CC + ks*32 + lg*8);
    }
    #pragma unroll
    for (int mt = 0; mt < 4; ++mt) {
      int ar = mt*16 + lr;
      s16x8 af[4];
      #pragma unroll
      for (int ks = 0; ks < 4; ++ks)
        af[ks] = *(const s16x8*)(src + ar*CC + swz8(ar, ks*32 + lg*8));
      #pragma unroll
      for (int ntl = 0; ntl < 2; ++ntl) {
        f32x4 a = {0.f,0.f,0.f,0.f};
        #pragma unroll
        for (int ks = 0; ks < 4; ++ks)
          a = __builtin_amdgcn_mfma_f32_16x16x32_bf16(af[ks], bfr[ntl][ks], a, 0,0,0);
        acc[mt][ntl] = a;
      }
    }
  };
  auto projW = [&](unsigned short* __restrict__ dst, f32x4 (&acc)[4][2], float (&bb)[2]) {
    #pragma unroll
    for (int mt = 0; mt < 4; ++mt) {
      #pragma unroll
      for (int ntl = 0; ntl < 2; ++ntl) {
        int col = wv*32 + ntl*16 + lr;
        int row0 = mt*16 + lg*4;          // C/D: row=(l>>4)*4+r, col=l&15
        unsigned int p01 = cvtpk(acc[mt][ntl][0]+bb[ntl], acc[mt][ntl][1]+bb[ntl]);
        unsigned int p23 = cvtpk(acc[mt][ntl][2]+bb[ntl], acc[mt][ntl][3]+bb[ntl]);
        if (row0   < NTOK) dst[ row0   *CC + swz8(row0,  col)] = (unsigned short)p01;
        if (row0+1 < NTOK) dst[(row0+1)*CC + swz8(row0+1,col)] = (unsigned short)(p01>>16);
        if (row0+2 < NTOK) dst[(row0+2)*CC + swz8(row0+2,col)] = (unsigned short)p23;
        if (row0+3 < NTOK) dst[(row0+3)*CC + swz8(row0+3,col)] = (unsigned short)(p23>>16);
      }
    }
  };

  // ---- R8-style separate projection phases (scheduling-stable)
  f32x4 acc[4][2]; float bb[2];
  projR(Buf0, Wbf, bq, SCALE_F, acc, bb);          // Q (scaled)
  __syncthreads();
  projW(Buf0, acc, bb);                            // Buf0 = Q
  projR(Buf1, Wbf + 16384, bk, 1.f, acc, bb);      // K
  __syncthreads();
  projW(Buf1, acc, bb);                            // Buf1 = K
  { // V projection: Buf2 -> VT (paired u32 writes; row0 even -> aligned)
    s16x8 bfr[2][4]; float vb[2];
    #pragma unroll
    for (int ntl = 0; ntl < 2; ++ntl) {
      int col = wv*32 + ntl*16 + lr;
      vb[ntl] = bv[col];
      #pragma unroll
      for (int ks = 0; ks < 4; ++ks)
        bfr[ntl][ks] = *(const s16x8*)(Wbf + 32768 + col*CC + ks*32 + lg*8);
    }
    #pragma unroll
    for (int mt = 0; mt < 4; ++mt) {
      int ar = mt*16 + lr;
      s16x8 af[4];
      #pragma unroll
      for (int ks = 0; ks < 4; ++ks)
        af[ks] = *(const s16x8*)(Buf2 + ar*CC + swz8(ar, ks*32 + lg*8));
      #pragma unroll
      for (int ntl = 0; ntl < 2; ++ntl) {
        f32x4 a = {0.f,0.f,0.f,0.f};
        #pragma unroll
        for (int ks = 0; ks < 4; ++ks)
          a = __builtin_amdgcn_mfma_f32_16x16x32_bf16(af[ks], bfr[ntl][ks], a, 0,0,0);
        int col = wv*32 + ntl*16 + lr;
        int row0 = mt*16 + lg*4;          // token, even -> u32 aligned
        unsigned int p01 = cvtpk(a[0]+vb[ntl], a[1]+vb[ntl]);
        unsigned int p23 = cvtpk(a[2]+vb[ntl], a[3]+vb[ntl]);
        int vbse = col*56 + row0;
        if (row0+1 < NTOK) *(unsigned int*)(VT + vbse) = p01;
        else if (row0 < NTOK) VT[vbse] = (unsigned short)p01;
        if (row0+3 < NTOK) *(unsigned int*)(VT + vbse + 2) = p23;
        else if (row0+2 < NTOK) VT[vbse+2] = (unsigned short)p23;
      }
    }
  }
  __syncthreads();

  // ---- Head section: wave wv owns head h=wv. S^T = K·Q^T via 32x32x16 MFMA.
  {
    const int h = wv;
    const float* Bh = Biasg + h*(NTOK*NTOK);   // [k][q], lane-consecutive in q
    s16x8 ak[2][2], av[4];
    #pragma unroll
    for (int kt = 0; kt < 2; ++kt) {
      int krow = kt*32 + c31; if (krow > 48) krow = 48;   // clamped rows masked later
      #pragma unroll
      for (int ks = 0; ks < 2; ++ks)
        ak[kt][ks] = *(const s16x8*)(Buf1 + krow*CC + swz8(krow, h*32 + ks*16 + hi*8));
    }
    #pragma unroll
    for (int kk = 0; kk < 4; ++kk)
      av[kk] = *(const s16x8*)(VT + (h*32 + c31)*56 + kk*16 + hi*8);
    size_t cbase = ((size_t)win*NHEADS + h)*(NTOK*NTOK);
    unsigned short* PL = Buf2 + h*1664;    // wave-local bounce [32][52] bf16 (8B rows)

    #pragma unroll
    for (int qh = 0; qh < 2; ++qh) {
      int q = qh*32 + c31;
      int qrow = q > 48 ? 48 : q;
      s16x8 bqf[2];
      #pragma unroll
      for (int ks = 0; ks < 2; ++ks)
        bqf[ks] = *(const s16x8*)(Buf0 + qrow*CC + swz8(qrow, h*32 + ks*16 + hi*8));
      f32x16 s0 = {0,0,0,0,0,0,0,0,0,0,0,0,0,0,0,0};
      f32x16 s1 = {0,0,0,0,0,0,0,0,0,0,0,0,0,0,0,0};
      s0 = __builtin_amdgcn_mfma_f32_32x32x16_bf16(ak[0][0], bqf[0], s0, 0,0,0);
      s0 = __builtin_amdgcn_mfma_f32_32x32x16_bf16(ak[0][1], bqf[1], s0, 0,0,0);
      s1 = __builtin_amdgcn_mfma_f32_32x32x16_bf16(ak[1][0], bqf[0], s1, 0,0,0);
      s1 = __builtin_amdgcn_mfma_f32_32x32x16_bf16(ak[1][1], bqf[1], s1, 0,0,0);
      // bias (precomputed table) + mask; D row=(r&3)+8*(r>>2)+4*hi, col=q
      float mx = -1e30f;
      #pragma unroll
      for (int r = 0; r < 16; ++r) {
        int kb = (r&3) + 8*(r>>2) + 4*hi;
        float v0 = -1e30f, v1 = -1e30f;
        if (q < NTOK) {
          v0 = s0[r] + Bh[kb*NTOK + q];
          if (kb + 32 < NTOK) v1 = s1[r] + Bh[(kb+32)*NTOK + q];
        }
        s0[r] = v0; mx = fmaxf(mx, v0);
        s1[r] = v1; mx = fmaxf(mx, v1);
      }
      mx = fmaxf(mx, __shfl_xor(mx, 32));
      float sum = 0.f;
      #pragma unroll
      for (int r = 0; r < 16; ++r) { s0[r] = __expf(s0[r]-mx); sum += s0[r]; }
      #pragma unroll
      for (int r = 0; r < 16; ++r) { s1[r] = __expf(s1[r]-mx); sum += s1[r]; }
      sum += __shfl_xor(sum, 32);
      float rinv = 1.f / sum;
      #pragma unroll
      for (int r = 0; r < 16; ++r) { s0[r] *= rinv; s1[r] *= rinv; }   // normalize
      // stash normalized P^T half: b64 stores, 4 consecutive k per group
      if (q < NTOK) {
        #pragma unroll
        for (int g = 0; g < 4; ++g) {
          u32x2 w;
          w[0] = cvtpk(s0[4*g],   s0[4*g+1]);
          w[1] = cvtpk(s0[4*g+2], s0[4*g+3]);
          *(u32x2*)(PL + c31*52 + g*8 + 4*hi) = w;
          int k2 = g*8 + 4*hi + 32;
          if (k2 <= 48) {
            u32x2 w2;
            w2[0] = cvtpk(s1[4*g],   s1[4*g+1]);
            w2[1] = cvtpk(s1[4*g+2], s1[4*g+3]);
            *(u32x2*)(PL + c31*52 + k2) = w2;
          }
        }
      }
      // PV: pack P^T bf16, exchange halves, out^T = V^T · P^T
      f32x16 pacc = {0,0,0,0,0,0,0,0,0,0,0,0,0,0,0,0};
      auto pvstep = [&](f32x16& e, const s16x8& a0, const s16x8& a1) {
        unsigned int w0m0 = cvtpk(e[0],e[1]),   w0m1 = cvtpk(e[2],e[3]);
        unsigned int w1m0 = cvtpk(e[4],e[5]),   w1m1 = cvtpk(e[6],e[7]);
        unsigned int w2m0 = cvtpk(e[8],e[9]),   w2m1 = cvtpk(e[10],e[11]);
        unsigned int w3m0 = cvtpk(e[12],e[13]), w3m1 = cvtpk(e[14],e[15]);
        unsigned int p0m0 = __shfl_xor((int)w0m0,32), p0m1 = __shfl_xor((int)w0m1,32);
        unsigned int p1m0 = __shfl_xor((int)w1m0,32), p1m1 = __shfl_xor((int)w1m1,32);
        unsigned int p2m0 = __shfl_xor((int)w2m0,32), p2m1 = __shfl_xor((int)w2m1,32);
        unsigned int p3m0 = __shfl_xor((int)w3m0,32), p3m1 = __shfl_xor((int)w3m1,32);
        FragU f;
        f.u[0] = hi ? p1m0 : w0m0;  f.u[1] = hi ? p1m1 : w0m1;
        f.u[2] = hi ? w1m0 : p0m0;  f.u[3] = hi ? w1m1 : p0m1;
        pacc = __builtin_amdgcn_mfma_f32_32x32x16_bf16(a0, f.v, pacc, 0,0,0);
        f.u[0] = hi ? p3m0 : w2m0;  f.u[1] = hi ? p3m1 : w2m1;
        f.u[2] = hi ? w3m0 : p2m0;  f.u[3] = hi ? w3m1 : p2m1;
        pacc = __builtin_amdgcn_mfma_f32_32x32x16_bf16(a1, f.v, pacc, 0,0,0);
      };
      pvstep(s0, av[0], av[1]);
      pvstep(s1, av[2], av[3]);
      { // coalesced ctx dump (wave-local; stride-52 rows)
        const int cnt = (qh == 0) ? 32*NTOK : 17*NTOK;
        size_t gb = cbase + (size_t)qh*32*NTOK;
        #pragma unroll
        for (int base = 0; base < 32*NTOK; base += 64) {
          int idx = base + l;
          if (idx < cnt) {
            int qq = idx / NTOK, kk2 = idx - qq*NTOK;
            out_ctx[gb + idx] = bf2f(PL[qq*52 + kk2]);
          }
        }
      }
      if (q < NTOK) { // attn-out into dead Q cols (bijective swz8 -> no collisions)
        #pragma unroll
        for (int r = 0; r < 16; ++r) {
          int d = (r&3) + 8*(r>>2) + 4*hi;
          Buf0[q*CC + swz8(q, h*32 + d)] = f2bf(pacc[r]);
        }
      }
    }
  }
  __syncthreads();

  { // output projection: x = attn_out @ Wo^T + bo, via LDS bounce (VT/Buf2 dead)
    const unsigned short* Wg = Wbf + 49152;
    float* Of = Obnc + wv*1600;     // [32ch][49tok] stride 50
    s16x8 bfr[2][4]; float ob[2];
    #pragma unroll
    for (int ntl = 0; ntl < 2; ++ntl) {
      int col = wv*32 + ntl*16 + lr;
      ob[ntl] = bo[col];
      #pragma unroll
      for (int ks = 0; ks < 4; ++ks)
        bfr[ntl][ks] = *(const s16x8*)(Wg + col*CC + ks*32 + lg*8);
    }
    #pragma unroll
    for (int mt = 0; mt < 4; ++mt) {
      int ar = mt*16 + lr;
      s16x8 af[4];
      #pragma unroll
      for (int ks = 0; ks < 4; ++ks)
        af[ks] = *(const s16x8*)(Buf0 + ar*CC + swz8(ar, ks*32 + lg*8));
      #pragma unroll
      for (int ntl = 0; ntl < 2; ++ntl) {
        f32x4 a = {0.f,0.f,0.f,0.f};
        #pragma unroll
        for (int ks = 0; ks < 4; ++ks)
          a = __builtin_amdgcn_mfma_f32_16x16x32_bf16(af[ks], bfr[ntl][ks], a, 0,0,0);
        #pragma unroll
        for (int r = 0; r < 4; ++r) {
          int row = mt*16 + lg*4 + r;
          if (row < NTOK)
            Of[(ntl*16 + lr)*50 + row] = a[r] + ob[ntl];
        }
      }
    }
    // wave-local dump: lane=linear element -> ~10 lines/inst instead of 64
    int chb = bimg*CC + wv*32;
    #pragma unroll
    for (int it = 0; it < 25; ++it) {
      int e = it*64 + l;
      if (e < 32*NTOK) {
        int ch = e / NTOK, tok = e - ch*NTOK;
        int si = tok / 7, sj = tok - si*7;
        out_x[(size_t)(chb + ch)*HW2 + (size_t)(r0+si)*HWW + (c0+sj)] = Of[ch*50 + tok];
      }
    }
  }
}

extern "C" void kernel_launch(void* const* d_in, const int* in_sizes, int n_in,
                              void* d_out, int out_size, void* d_ws, size_t ws_size,
                              hipStream_t stream) {
  (void)in_sizes; (void)n_in; (void)out_size; (void)ws_size;
  const float* query = (const float*)d_in[0];
  const float* key   = (const float*)d_in[1];
  const float* value = (const float*)d_in[2];
  const float* Wq = (const float*)d_in[3];
  const float* bq = (const float*)d_in[4];
  const float* Wk = (const float*)d_in[5];
  const float* bk = (const float*)d_in[6];
  const float* Wv = (const float*)d_in[7];
  const float* bv = (const float*)d_in[8];
  const float* Wo = (const float*)d_in[9];
  const float* bo = (const float*)d_in[10];
  const float* rpb = (const float*)d_in[11];

  unsigned short* Wbf = (unsigned short*)d_ws;                  // 128 KB bf16 weights
  float* Biasg = (float*)((char*)d_ws + 131072);                // 38.4 KB bias table
  float* out_x   = (float*)d_out;                               // [64][128][56][56] fp32
  float* out_ctx = out_x + (size_t)64*CC*HW2;                   // [4096][4][49][49] fp32

  prep_kernel<<<294, 256, 0, stream>>>(Wq, Wk, Wv, Wo, rpb, Wbf, Biasg);
  winattn_kernel<<<4096, 256, 0, stream>>>(query, key, value, Wbf, Biasg,
                                           bq, bk, bv, bo, out_x, out_ctx);
}

// Round 13
// 265.512 us; speedup vs baseline: 1.0354x; 1.0019x over previous
//
#include <hip/hip_runtime.h>

#define NTOK 49
#define CC   128
#define NHEADS 4
#define HWW  56
#define HW2  3136
#define SCALE_F 0.17677669529663687f

typedef __attribute__((ext_vector_type(8))) short s16x8;
typedef __attribute__((ext_vector_type(4))) float f32x4;
typedef __attribute__((ext_vector_type(16))) float f32x16;
typedef __attribute__((ext_vector_type(2))) unsigned int u32x2;

static __device__ __forceinline__ unsigned short f2bf(float f) {
  unsigned int u = __float_as_uint(f);
  u += 0x7fffu + ((u >> 16) & 1u);
  return (unsigned short)(u >> 16);
}
static __device__ __forceinline__ float bf2f(unsigned short h) {
  return __uint_as_float(((unsigned int)h) << 16);
}
// HW packed f32->bf16 (RNE), 1 VALU op for 2 values
static __device__ __forceinline__ unsigned int cvtpk(float lo, float hi) {
  unsigned int r;
  asm("v_cvt_pk_bf16_f32 %0, %1, %2" : "=v"(r) : "v"(lo), "v"(hi));
  return r;
}
// row-keyed bijective swizzle: flips col bits 3-5 by row&7, bit 6 by row bit 3
// -> 16 bank-slot spread; keeps 8-elem groups contiguous. ALL Buf0/1/2 access.
static __device__ __forceinline__ int swz8(int row, int col) {
  return col ^ ((row & 7) << 3) ^ ((row & 8) << 3);
}

union FragU { s16x8 v; unsigned int u[4]; };

// prep: weights -> bf16 (scale folded into Wq) + bias table Biasg[h][k][q]
__global__ void prep_kernel(const float* __restrict__ Wq, const float* __restrict__ Wk,
                            const float* __restrict__ Wv, const float* __restrict__ Wo,
                            const float* __restrict__ rpb,
                            unsigned short* __restrict__ dstW, float* __restrict__ dstB) {
  int i = blockIdx.x * 256 + threadIdx.x;
  if (i < 65536) {
    const float* src = (i < 16384) ? Wq : (i < 32768) ? Wk : (i < 49152) ? Wv : Wo;
    float v = src[i & 16383];
    if (i < 16384) v *= SCALE_F;
    dstW[i] = f2bf(v);
  } else {
    int j = i - 65536;
    if (j < NHEADS*NTOK*NTOK) {
      int h = j / (NTOK*NTOK), rem = j - h*(NTOK*NTOK);
      int k = rem / NTOK, q = rem - k*NTOK;
      int qi = q/7, qj = q - qi*7, ki = k/7, kj = k - ki*7;
      dstB[j] = rpb[((qi-ki+6)*13 + (qj-kj+6))*NHEADS + h];
    }
  }
}

__global__ __launch_bounds__(256, 3)
void winattn_kernel(const float* __restrict__ Xq, const float* __restrict__ Xk,
                    const float* __restrict__ Xv,
                    const unsigned short* __restrict__ Wbf,
                    const float* __restrict__ Biasg,
                    const float* __restrict__ bq, const float* __restrict__ bk,
                    const float* __restrict__ bv, const float* __restrict__ bo,
                    float* __restrict__ out_x,
                    float* __restrict__ out_ctx)
{
  // 52736 B total -> 3 blocks/CU
  __shared__ alignas(16) unsigned short smem[26368];
  unsigned short* Buf0 = smem;            // [49][128] raw q -> Q -> attn-out (swz8)
  unsigned short* Buf1 = smem + 6272;     // [49][128] raw k -> K (swz8)
  unsigned short* VT   = smem + 12544;    // [128][56]: (h*32+d) x token, V^T
  unsigned short* Buf2 = smem + 19712;    // [49][128] raw v (swz8) -> P bounce [4][32*52]
  float* Obnc = (float*)(smem + 12544);   // epilogue bounce [4 waves][32ch][49tok] stride 50

  const int tid = threadIdx.x;
  const int wv  = tid >> 6;
  const int l   = tid & 63;
  const int lr  = l & 15;   // 16x16 MFMA lane row/col
  const int lg  = l >> 4;   // 16x16 MFMA k-group
  const int c31 = l & 31;   // 32x32 MFMA lane col
  const int hi  = l >> 5;   // 32x32 MFMA half

  // XCD-bijective swizzle (4096 % 8 == 0): same-band windows share an XCD L2
  const int win  = (blockIdx.x & 7) * 512 + (blockIdx.x >> 3);
  const int bimg = win >> 6;
  const int r0   = ((win >> 3) & 7) * 7;
  const int c0   = (win & 7) * 7;

  // ---- Phase 0: zero VT + stage q,k,v (lane=token; b64 LDS stores, cvt_pk packing)
  {
    unsigned int* vz = (unsigned int*)VT;
    #pragma unroll
    for (int i = 0; i < 14; ++i) vz[tid + i*256] = 0u;   // 14336 B
    int s = tid & 63, g = tid >> 6;
    if (s < NTOK) {
      int si = s / 7, sj = s - si*7;
      size_t base = (size_t)bimg*CC*HW2 + (size_t)(r0+si)*HWW + (c0+sj);
      #pragma unroll 4
      for (int cp = 0; cp < 8; ++cp) {
        int ci = g*32 + cp*4;
        size_t off = base + (size_t)ci * HW2;
        float q0 = Xq[off], q1 = Xq[off+HW2], q2 = Xq[off+2*HW2], q3 = Xq[off+3*HW2];
        float k0 = Xk[off], k1 = Xk[off+HW2], k2 = Xk[off+2*HW2], k3 = Xk[off+3*HW2];
        float v0 = Xv[off], v1 = Xv[off+HW2], v2 = Xv[off+2*HW2], v3 = Xv[off+3*HW2];
        int di = s*CC + swz8(s, ci);                  // 8B-aligned (swz8 keeps bits 0-2)
        u32x2 pq = {cvtpk(q0,q1), cvtpk(q2,q3)};
        u32x2 pk = {cvtpk(k0,k1), cvtpk(k2,k3)};
        u32x2 pv = {cvtpk(v0,v1), cvtpk(v2,v3)};
        *(u32x2*)(Buf0 + di) = pq;
        *(u32x2*)(Buf1 + di) = pk;
        *(u32x2*)(Buf2 + di) = pv;
      }
    }
  }
  __syncthreads();

  // proj read-half: acc[mt][ntl] = src * W^T (bias folded at write)
  auto projR = [&](const unsigned short* __restrict__ src, const unsigned short* __restrict__ Wg,
                   const float* __restrict__ bias, float bscale,
                   f32x4 (&acc)[4][2], float (&bb)[2]) {
    s16x8 bfr[2][4];
    #pragma unroll
    for (int ntl = 0; ntl < 2; ++ntl) {
      int col = wv*32 + ntl*16 + lr;
      bb[ntl] = bias[col] * bscale;
      #pragma unroll
      for (int ks = 0; ks < 4; ++ks)
        bfr[ntl][ks] = *(const s16x8*)(Wg + col*CC + ks*32 + lg*8);
    }
    #pragma unroll
    for (int mt = 0; mt < 4; ++mt) {
      int ar = mt*16 + lr;
      s16x8 af[4];
      #pragma unroll
      for (int ks = 0; ks < 4; ++ks)
        af[ks] = *(const s16x8*)(src + ar*CC + swz8(ar, ks*32 + lg*8));
      #pragma unroll
      for (int ntl = 0; ntl < 2; ++ntl) {
        f32x4 a = {0.f,0.f,0.f,0.f};
        #pragma unroll
        for (int ks = 0; ks < 4; ++ks)
          a = __builtin_amdgcn_mfma_f32_16x16x32_bf16(af[ks], bfr[ntl][ks], a, 0,0,0);
        acc[mt][ntl] = a;
      }
    }
  };
  auto projW = [&](unsigned short* __restrict__ dst, f32x4 (&acc)[4][2], float (&bb)[2]) {
    #pragma unroll
    for (int mt = 0; mt < 4; ++mt) {
      #pragma unroll
      for (int ntl = 0; ntl < 2; ++ntl) {
        int col = wv*32 + ntl*16 + lr;
        int row0 = mt*16 + lg*4;          // C/D: row=(l>>4)*4+r, col=l&15
        unsigned int p01 = cvtpk(acc[mt][ntl][0]+bb[ntl], acc[mt][ntl][1]+bb[ntl]);
        unsigned int p23 = cvtpk(acc[mt][ntl][2]+bb[ntl], acc[mt][ntl][3]+bb[ntl]);
        if (row0   < NTOK) dst[ row0   *CC + swz8(row0,  col)] = (unsigned short)p01;
        if (row0+1 < NTOK) dst[(row0+1)*CC + swz8(row0+1,col)] = (unsigned short)(p01>>16);
        if (row0+2 < NTOK) dst[(row0+2)*CC + swz8(row0+2,col)] = (unsigned short)p23;
        if (row0+3 < NTOK) dst[(row0+3)*CC + swz8(row0+3,col)] = (unsigned short)(p23>>16);
      }
    }
  };

  // ---- R8-style separate projection phases (scheduling-stable)
  f32x4 acc[4][2]; float bb[2];
  projR(Buf0, Wbf, bq, SCALE_F, acc, bb);          // Q (scaled)
  __syncthreads();
  projW(Buf0, acc, bb);                            // Buf0 = Q
  projR(Buf1, Wbf + 16384, bk, 1.f, acc, bb);      // K
  __syncthreads();
  projW(Buf1, acc, bb);                            // Buf1 = K
  { // V projection: Buf2 -> VT (paired u32 writes; row0 even -> aligned)
    s16x8 bfr[2][4]; float vb[2];
    #pragma unroll
    for (int ntl = 0; ntl < 2; ++ntl) {
      int col = wv*32 + ntl*16 + lr;
      vb[ntl] = bv[col];
      #pragma unroll
      for (int ks = 0; ks < 4; ++ks)
        bfr[ntl][ks] = *(const s16x8*)(Wbf + 32768 + col*CC + ks*32 + lg*8);
    }
    #pragma unroll
    for (int mt = 0; mt < 4; ++mt) {
      int ar = mt*16 + lr;
      s16x8 af[4];
      #pragma unroll
      for (int ks = 0; ks < 4; ++ks)
        af[ks] = *(const s16x8*)(Buf2 + ar*CC + swz8(ar, ks*32 + lg*8));
      #pragma unroll
      for (int ntl = 0; ntl < 2; ++ntl) {
        f32x4 a = {0.f,0.f,0.f,0.f};
        #pragma unroll
        for (int ks = 0; ks < 4; ++ks)
          a = __builtin_amdgcn_mfma_f32_16x16x32_bf16(af[ks], bfr[ntl][ks], a, 0,0,0);
        int col = wv*32 + ntl*16 + lr;
        int row0 = mt*16 + lg*4;          // token, even -> u32 aligned
        unsigned int p01 = cvtpk(a[0]+vb[ntl], a[1]+vb[ntl]);
        unsigned int p23 = cvtpk(a[2]+vb[ntl], a[3]+vb[ntl]);
        int vbse = col*56 + row0;
        if (row0+1 < NTOK) *(unsigned int*)(VT + vbse) = p01;
        else if (row0 < NTOK) VT[vbse] = (unsigned short)p01;
        if (row0+3 < NTOK) *(unsigned int*)(VT + vbse + 2) = p23;
        else if (row0+2 < NTOK) VT[vbse+2] = (unsigned short)p23;
      }
    }
  }
  __syncthreads();

  // ---- Head section: wave wv owns head h=wv. S^T = K·Q^T via 32x32x16 MFMA.
  {
    const int h = wv;
    const float* Bh = Biasg + h*(NTOK*NTOK);   // [k][q], lane-consecutive in q
    s16x8 ak[2][2], av[4];
    #pragma unroll
    for (int kt = 0; kt < 2; ++kt) {
      int krow = kt*32 + c31; if (krow > 48) krow = 48;   // clamped rows masked later
      #pragma unroll
      for (int ks = 0; ks < 2; ++ks)
        ak[kt][ks] = *(const s16x8*)(Buf1 + krow*CC + swz8(krow, h*32 + ks*16 + hi*8));
    }
    #pragma unroll
    for (int kk = 0; kk < 4; ++kk)
      av[kk] = *(const s16x8*)(VT + (h*32 + c31)*56 + kk*16 + hi*8);
    size_t cbase = ((size_t)win*NHEADS + h)*(NTOK*NTOK);
    unsigned short* PL = Buf2 + h*1664;    // wave-local bounce [32][52] bf16 (8B rows)

    #pragma unroll
    for (int qh = 0; qh < 2; ++qh) {
      int q = qh*32 + c31;
      int qrow = q > 48 ? 48 : q;
      s16x8 bqf[2];
      #pragma unroll
      for (int ks = 0; ks < 2; ++ks)
        bqf[ks] = *(const s16x8*)(Buf0 + qrow*CC + swz8(qrow, h*32 + ks*16 + hi*8));
      f32x16 s0 = {0,0,0,0,0,0,0,0,0,0,0,0,0,0,0,0};
      f32x16 s1 = {0,0,0,0,0,0,0,0,0,0,0,0,0,0,0,0};
      s0 = __builtin_amdgcn_mfma_f32_32x32x16_bf16(ak[0][0], bqf[0], s0, 0,0,0);
      s0 = __builtin_amdgcn_mfma_f32_32x32x16_bf16(ak[0][1], bqf[1], s0, 0,0,0);
      s1 = __builtin_amdgcn_mfma_f32_32x32x16_bf16(ak[1][0], bqf[0], s1, 0,0,0);
      s1 = __builtin_amdgcn_mfma_f32_32x32x16_bf16(ak[1][1], bqf[1], s1, 0,0,0);
      // bias (precomputed table) + mask; D row=(r&3)+8*(r>>2)+4*hi, col=q
      float mx = -1e30f;
      #pragma unroll
      for (int r = 0; r < 16; ++r) {
        int kb = (r&3) + 8*(r>>2) + 4*hi;
        float v0 = -1e30f, v1 = -1e30f;
        if (q < NTOK) {
          v0 = s0[r] + Bh[kb*NTOK + q];
          if (kb + 32 < NTOK) v1 = s1[r] + Bh[(kb+32)*NTOK + q];
        }
        s0[r] = v0; mx = fmaxf(mx, v0);
        s1[r] = v1; mx = fmaxf(mx, v1);
      }
      mx = fmaxf(mx, __shfl_xor(mx, 32));
      float sum = 0.f;
      #pragma unroll
      for (int r = 0; r < 16; ++r) { s0[r] = __expf(s0[r]-mx); sum += s0[r]; }
      #pragma unroll
      for (int r = 0; r < 16; ++r) { s1[r] = __expf(s1[r]-mx); sum += s1[r]; }
      sum += __shfl_xor(sum, 32);
      float rinv = 1.f / sum;
      #pragma unroll
      for (int r = 0; r < 16; ++r) { s0[r] *= rinv; s1[r] *= rinv; }   // normalize
      // stash normalized P^T half: b64 stores, 4 consecutive k per group
      if (q < NTOK) {
        #pragma unroll
        for (int g = 0; g < 4; ++g) {
          u32x2 w;
          w[0] = cvtpk(s0[4*g],   s0[4*g+1]);
          w[1] = cvtpk(s0[4*g+2], s0[4*g+3]);
          *(u32x2*)(PL + c31*52 + g*8 + 4*hi) = w;
          int k2 = g*8 + 4*hi + 32;
          if (k2 <= 48) {
            u32x2 w2;
            w2[0] = cvtpk(s1[4*g],   s1[4*g+1]);
            w2[1] = cvtpk(s1[4*g+2], s1[4*g+3]);
            *(u32x2*)(PL + c31*52 + k2) = w2;
          }
        }
      }
      // PV: pack P^T bf16, exchange halves, out^T = V^T · P^T
      f32x16 pacc = {0,0,0,0,0,0,0,0,0,0,0,0,0,0,0,0};
      auto pvstep = [&](f32x16& e, const s16x8& a0, const s16x8& a1) {
        unsigned int w0m0 = cvtpk(e[0],e[1]),   w0m1 = cvtpk(e[2],e[3]);
        unsigned int w1m0 = cvtpk(e[4],e[5]),   w1m1 = cvtpk(e[6],e[7]);
        unsigned int w2m0 = cvtpk(e[8],e[9]),   w2m1 = cvtpk(e[10],e[11]);
        unsigned int w3m0 = cvtpk(e[12],e[13]), w3m1 = cvtpk(e[14],e[15]);
        unsigned int p0m0 = __shfl_xor((int)w0m0,32), p0m1 = __shfl_xor((int)w0m1,32);
        unsigned int p1m0 = __shfl_xor((int)w1m0,32), p1m1 = __shfl_xor((int)w1m1,32);
        unsigned int p2m0 = __shfl_xor((int)w2m0,32), p2m1 = __shfl_xor((int)w2m1,32);
        unsigned int p3m0 = __shfl_xor((int)w3m0,32), p3m1 = __shfl_xor((int)w3m1,32);
        FragU f;
        f.u[0] = hi ? p1m0 : w0m0;  f.u[1] = hi ? p1m1 : w0m1;
        f.u[2] = hi ? w1m0 : p0m0;  f.u[3] = hi ? w1m1 : p0m1;
        pacc = __builtin_amdgcn_mfma_f32_32x32x16_bf16(a0, f.v, pacc, 0,0,0);
        f.u[0] = hi ? p3m0 : w2m0;  f.u[1] = hi ? p3m1 : w2m1;
        f.u[2] = hi ? w3m0 : p2m0;  f.u[3] = hi ? w3m1 : p2m1;
        pacc = __builtin_amdgcn_mfma_f32_32x32x16_bf16(a1, f.v, pacc, 0,0,0);
      };
      pvstep(s0, av[0], av[1]);
      pvstep(s1, av[2], av[3]);
      { // coalesced ctx dump (wave-local; stride-52 rows)
        const int cnt = (qh == 0) ? 32*NTOK : 17*NTOK;
        size_t gb = cbase + (size_t)qh*32*NTOK;
        #pragma unroll
        for (int base = 0; base < 32*NTOK; base += 64) {
          int idx = base + l;
          if (idx < cnt) {
            int qq = idx / NTOK, kk2 = idx - qq*NTOK;
            out_ctx[gb + idx] = bf2f(PL[qq*52 + kk2]);
          }
        }
      }
      if (q < NTOK) { // attn-out into dead Q cols (bijective swz8 -> no collisions)
        #pragma unroll
        for (int r = 0; r < 16; ++r) {
          int d = (r&3) + 8*(r>>2) + 4*hi;
          Buf0[q*CC + swz8(q, h*32 + d)] = f2bf(pacc[r]);
        }
      }
    }
  }
  __syncthreads();

  { // output projection: x = attn_out @ Wo^T + bo, via LDS bounce (VT/Buf2 dead)
    const unsigned short* Wg = Wbf + 49152;
    float* Of = Obnc + wv*1600;     // [32ch][49tok] stride 50
    s16x8 bfr[2][4]; float ob[2];
    #pragma unroll
    for (int ntl = 0; ntl < 2; ++ntl) {
      int col = wv*32 + ntl*16 + lr;
      ob[ntl] = bo[col];
      #pragma unroll
      for (int ks = 0; ks < 4; ++ks)
        bfr[ntl][ks] = *(const s16x8*)(Wg + col*CC + ks*32 + lg*8);
    }
    #pragma unroll
    for (int mt = 0; mt < 4; ++mt) {
      int ar = mt*16 + lr;
      s16x8 af[4];
      #pragma unroll
      for (int ks = 0; ks < 4; ++ks)
        af[ks] = *(const s16x8*)(Buf0 + ar*CC + swz8(ar, ks*32 + lg*8));
      #pragma unroll
      for (int ntl = 0; ntl < 2; ++ntl) {
        f32x4 a = {0.f,0.f,0.f,0.f};
        #pragma unroll
        for (int ks = 0; ks < 4; ++ks)
          a = __builtin_amdgcn_mfma_f32_16x16x32_bf16(af[ks], bfr[ntl][ks], a, 0,0,0);
        #pragma unroll
        for (int r = 0; r < 4; ++r) {
          int row = mt*16 + lg*4 + r;
          if (row < NTOK)
            Of[(ntl*16 + lr)*50 + row] = a[r] + ob[ntl];
        }
      }
    }
    // wave-local dump: lane=linear element -> ~10 lines/inst instead of 64
    int chb = bimg*CC + wv*32;
    #pragma unroll
    for (int it = 0; it < 25; ++it) {
      int e = it*64 + l;
      if (e < 32*NTOK) {
        int ch = e / NTOK, tok = e - ch*NTOK;
        int si = tok / 7, sj = tok - si*7;
        out_x[(size_t)(chb + ch)*HW2 + (size_t)(r0+si)*HWW + (c0+sj)] = Of[ch*50 + tok];
      }
    }
  }
}

extern "C" void kernel_launch(void* const* d_in, const int* in_sizes, int n_in,
                              void* d_out, int out_size, void* d_ws, size_t ws_size,
                              hipStream_t stream) {
  (void)in_sizes; (void)n_in; (void)out_size; (void)ws_size;
  const float* query = (const float*)d_in[0];
  const float* key   = (const float*)d_in[1];
  const float* value = (const float*)d_in[2];
  const float* Wq = (const float*)d_in[3];
  const float* bq = (const float*)d_in[4];
  const float* Wk = (const float*)d_in[5];
  const float* bk = (const float*)d_in[6];
  const float* Wv = (const float*)d_in[7];
  const float* bv = (const float*)d_in[8];
  const float* Wo = (const float*)d_in[9];
  const float* bo = (const float*)d_in[10];
  const float* rpb = (const float*)d_in[11];

  unsigned short* Wbf = (unsigned short*)d_ws;                  // 128 KB bf16 weights
  float* Biasg = (float*)((char*)d_ws + 131072);                // 38.4 KB bias table
  float* out_x   = (float*)d_out;                               // [64][128][56][56] fp32
  float* out_ctx = out_x + (size_t)64*CC*HW2;                   // [4096][4][49][49] fp32

  prep_kernel<<<294, 256, 0, stream>>>(Wq, Wk, Wv, Wo, rpb, Wbf, Biasg);
  winattn_kernel<<<4096, 256, 0, stream>>>(query, key, value, Wbf, Biasg,
                                           bq, bk, bv, bo, out_x, out_ctx);
}